// Round 2
// baseline (71.572 us; speedup 1.0000x reference)
//
#include <hip/hip_runtime.h>

typedef __attribute__((ext_vector_type(4))) float f32x4;
typedef __attribute__((ext_vector_type(8))) short bf16x8;

// f32 -> bf16 round-to-nearest-even
__device__ inline unsigned short f2bf(float x) {
  unsigned u = __builtin_bit_cast(unsigned, x);
  u += 0x7fffu + ((u >> 16) & 1u);
  return (unsigned short)(u >> 16);
}

__device__ inline bf16x8 pack8(f32x4 lo, f32x4 hi) {
  bf16x8 r;
  r[0] = (short)f2bf(lo[0]); r[1] = (short)f2bf(lo[1]);
  r[2] = (short)f2bf(lo[2]); r[3] = (short)f2bf(lo[3]);
  r[4] = (short)f2bf(hi[0]); r[5] = (short)f2bf(hi[1]);
  r[6] = (short)f2bf(hi[2]); r[7] = (short)f2bf(hi[3]);
  return r;
}

__device__ inline bf16x8 cvt8(const float* __restrict__ p) {
  return pack8(*(const f32x4*)p, *(const f32x4*)(p + 4));
}

// GEMM1: e[2048][128] = X @ Wr^T + br  (bf16 out). Block: 64 tok x 64 n,
// LDS-staged with shared f32->bf16 cvt; prefetch next chunk into regs.
__global__ __launch_bounds__(256) void gemm1_kernel(
    const float* __restrict__ X, const float* __restrict__ Wr,
    const float* __restrict__ br, unsigned short* __restrict__ Ebf) {
  __shared__ unsigned short Xs[64][40];  // 40 = 32 + pad (80B rows: 2-way banks)
  __shared__ unsigned short Ws[64][40];

  int tid = threadIdx.x;
  int wave = tid >> 6, lane = tid & 63;
  int tok0 = blockIdx.x * 64;
  int n0 = blockIdx.y * 64;

  int srow = tid >> 2;          // 0..63
  int scol = (tid & 3) * 8;     // 0,8,16,24
  const float* xp = X + (size_t)(tok0 + srow) * 768 + scol;
  const float* wp = Wr + (size_t)(n0 + srow) * 768 + scol;

  int lr = lane & 15;
  int kg = (lane >> 4) * 8;

  f32x4 acc0 = {0,0,0,0}, acc1 = {0,0,0,0}, acc2 = {0,0,0,0}, acc3 = {0,0,0,0};

  f32x4 x0 = *(const f32x4*)xp;
  f32x4 x1 = *(const f32x4*)(xp + 4);
  f32x4 w0 = *(const f32x4*)wp;
  f32x4 w1 = *(const f32x4*)(wp + 4);

  for (int ks = 0; ks < 24; ++ks) {
    __syncthreads();  // prior MFMA-phase LDS reads complete
    *(bf16x8*)&Xs[srow][scol] = pack8(x0, x1);
    *(bf16x8*)&Ws[srow][scol] = pack8(w0, w1);
    __syncthreads();  // staging visible
    if (ks < 23) {
      int off = (ks + 1) * 32;
      x0 = *(const f32x4*)(xp + off);
      x1 = *(const f32x4*)(xp + off + 4);
      w0 = *(const f32x4*)(wp + off);
      w1 = *(const f32x4*)(wp + off + 4);
    }
    bf16x8 a = *(const bf16x8*)&Xs[wave * 16 + lr][kg];
    bf16x8 b0 = *(const bf16x8*)&Ws[lr][kg];
    bf16x8 b1 = *(const bf16x8*)&Ws[16 + lr][kg];
    bf16x8 b2v = *(const bf16x8*)&Ws[32 + lr][kg];
    bf16x8 b3 = *(const bf16x8*)&Ws[48 + lr][kg];
    acc0 = __builtin_amdgcn_mfma_f32_16x16x32_bf16(a, b0, acc0, 0, 0, 0);
    acc1 = __builtin_amdgcn_mfma_f32_16x16x32_bf16(a, b1, acc1, 0, 0, 0);
    acc2 = __builtin_amdgcn_mfma_f32_16x16x32_bf16(a, b2v, acc2, 0, 0, 0);
    acc3 = __builtin_amdgcn_mfma_f32_16x16x32_bf16(a, b3, acc3, 0, 0, 0);
  }

  int rb = (lane >> 4) * 4;
  f32x4 accs[4] = {acc0, acc1, acc2, acc3};
#pragma unroll
  for (int t = 0; t < 4; ++t) {
    int n = n0 + t * 16 + lr;
    float bias = br[n];
#pragma unroll
    for (int r = 0; r < 4; ++r) {
      int tok = tok0 + wave * 16 + rb + r;
      Ebf[(size_t)tok * 128 + n] = f2bf(accs[t][r] + bias);
    }
  }
}

// GEMM2: UVt[512][2048]; rows 0..255 = u'(e@W1_row^T + b1), 256..511 = v.
// Wave: 16 m x 64 tok (4 tiles), K=128 fully unrolled, no LDS/barriers.
__global__ __launch_bounds__(256) void gemm2_kernel(
    const unsigned short* __restrict__ Ebf, const float* __restrict__ W1,
    const float* __restrict__ b1, float* __restrict__ UVt) {
  int wave = threadIdx.x >> 6, lane = threadIdx.x & 63;
  int t0 = blockIdx.x * 64;
  int m0 = (blockIdx.y * 4 + wave) * 16;
  int lr = lane & 15, kg = (lane >> 4) * 8;
  const float* aBase = (m0 < 256)
      ? (W1 + (size_t)(m0 + lr) * 256 + kg)
      : (W1 + (size_t)(m0 - 256 + lr) * 256 + 128 + kg);
  f32x4 acc[4] = {{0,0,0,0},{0,0,0,0},{0,0,0,0},{0,0,0,0}};
#pragma unroll
  for (int k0 = 0; k0 < 128; k0 += 32) {
    bf16x8 a = cvt8(aBase + k0);
#pragma unroll
    for (int t = 0; t < 4; ++t) {
      bf16x8 b = *(const bf16x8*)(const void*)(Ebf + (size_t)(t0 + t * 16 + lr) * 128 + kg + k0);
      acc[t] = __builtin_amdgcn_mfma_f32_16x16x32_bf16(a, b, acc[t], 0, 0, 0);
    }
  }
  int rb = (lane >> 4) * 4;
#pragma unroll
  for (int t = 0; t < 4; ++t) {
#pragma unroll
    for (int r = 0; r < 4; ++r) {
      int m = m0 + rb + r;
      float bias = (m < 256) ? b1[m] : 0.f;
      UVt[(size_t)m * 2048 + t0 + t * 16 + lr] = acc[t][r] + bias;
    }
  }
}

// cvec[h*2048+tok] = 0.5 * sum_m w2[m]*UVt[h*256+m][tok]  (+b2 for h==0)
__global__ __launch_bounds__(256) void cvec_kernel(
    const float* __restrict__ UVt, const float* __restrict__ W2,
    const float* __restrict__ b2p, float* __restrict__ cvec) {
  int h = blockIdx.y;
  int tok = blockIdx.x * 256 + threadIdx.x;
  const float* base = UVt + (size_t)h * 256 * 2048 + tok;
  float a0 = 0.f, a1 = 0.f, a2 = 0.f, a3 = 0.f;
#pragma unroll 4
  for (int m = 0; m < 256; m += 4) {
    a0 = fmaf(W2[m], base[(size_t)m * 2048], a0);
    a1 = fmaf(W2[m + 1], base[(size_t)(m + 1) * 2048], a1);
    a2 = fmaf(W2[m + 2], base[(size_t)(m + 2) * 2048], a2);
    a3 = fmaf(W2[m + 3], base[(size_t)(m + 3) * 2048], a3);
  }
  float r = 0.5f * ((a0 + a1) + (a2 + a3)) + (h == 0 ? b2p[0] : 0.f);
  cvec[h * 2048 + tok] = r;
}

// Pairwise: out[b,i,j] = cu[i] + cv[j] + 0.5*sum_m w2[m]*|u[i,m]+v[j,m]|
// 16x16 tile per 1-wave block; upper-tri tile pairs only, mirrored via LDS.
__global__ __launch_bounds__(64) void pairwise_kernel(
    const float* __restrict__ UVt, const float* __restrict__ W2,
    const float* __restrict__ cvec, float* __restrict__ Out) {
  __shared__ float u_s[16][132];   // [tok][m], pad 132 (2-way banks on b128)
  __shared__ float v_s[16][132];
  __shared__ float w2_s[256];
  __shared__ float t_s[16][17];

  int tid = threadIdx.x;
  int b = blockIdx.y;
  int p = blockIdx.x;
  int it = 0;
  while (p >= 64 - it) { p -= 64 - it; ++it; }
  int jt = it + p;

  *(f32x4*)&w2_s[4 * tid] = *(const f32x4*)&W2[4 * tid];

  int tx = tid & 7, ty = tid >> 3;
  int utok = b * 1024 + it * 16;
  int vtok = b * 1024 + jt * 16;

  int mrow = tid >> 2;        // 0..15
  int tokq = (tid & 3) * 4;   // 0,4,8,12

  float acc00 = 0.f, acc01 = 0.f, acc10 = 0.f, acc11 = 0.f;

  for (int mc = 0; mc < 2; ++mc) {
    int M0 = mc * 128;
    __syncthreads();
#pragma unroll
    for (int g = 0; g < 8; ++g) {
      int ml = g * 16 + mrow;
      int m = M0 + ml;
      f32x4 uu = *(const f32x4*)(UVt + (size_t)m * 2048 + utok + tokq);
      f32x4 vv = *(const f32x4*)(UVt + (size_t)(256 + m) * 2048 + vtok + tokq);
#pragma unroll
      for (int k = 0; k < 4; ++k) {
        u_s[tokq + k][ml] = uu[k];
        v_s[tokq + k][ml] = vv[k];
      }
    }
    __syncthreads();
#pragma unroll 8
    for (int g = 0; g < 32; ++g) {
      f32x4 wv = *(const f32x4*)&w2_s[M0 + 4 * g];
      f32x4 ua = *(const f32x4*)&u_s[2 * ty][4 * g];
      f32x4 ub = *(const f32x4*)&u_s[2 * ty + 1][4 * g];
      f32x4 va = *(const f32x4*)&v_s[2 * tx][4 * g];
      f32x4 vb = *(const f32x4*)&v_s[2 * tx + 1][4 * g];
#pragma unroll
      for (int k = 0; k < 4; ++k) {
        acc00 = fmaf(wv[k], fabsf(ua[k] + va[k]), acc00);
        acc01 = fmaf(wv[k], fabsf(ua[k] + vb[k]), acc01);
        acc10 = fmaf(wv[k], fabsf(ub[k] + va[k]), acc10);
        acc11 = fmaf(wv[k], fabsf(ub[k] + vb[k]), acc11);
      }
    }
  }

  float cu0 = cvec[utok + 2 * ty], cu1 = cvec[utok + 2 * ty + 1];
  float cv0 = cvec[2048 + vtok + 2 * tx], cv1 = cvec[2048 + vtok + 2 * tx + 1];

  __syncthreads();
  t_s[2 * ty][2 * tx]         = cu0 + cv0 + 0.5f * acc00;
  t_s[2 * ty][2 * tx + 1]     = cu0 + cv1 + 0.5f * acc01;
  t_s[2 * ty + 1][2 * tx]     = cu1 + cv0 + 0.5f * acc10;
  t_s[2 * ty + 1][2 * tx + 1] = cu1 + cv1 + 0.5f * acc11;
  __syncthreads();

  int il = tid >> 2;  // 0..15
  int jq = tid & 3;   // 0..3
  size_t obase = (size_t)b << 20;
  if (it != jt) {
    f32x4 dv, mv;
#pragma unroll
    for (int k = 0; k < 4; ++k) {
      dv[k] = t_s[il][4 * jq + k];
      mv[k] = t_s[4 * jq + k][il];
    }
    *(f32x4*)(Out + obase + (size_t)(it * 16 + il) * 1024 + jt * 16 + 4 * jq) = dv;
    *(f32x4*)(Out + obase + (size_t)(jt * 16 + il) * 1024 + it * 16 + 4 * jq) = mv;
  } else {
#pragma unroll
    for (int k = 0; k < 4; ++k) {
      int jl = 4 * jq + k;
      float v = t_s[il][jl];
      if (jl >= il) Out[obase + (size_t)(it * 16 + il) * 1024 + it * 16 + jl] = v;
      if (jl > il)  Out[obase + (size_t)(it * 16 + jl) * 1024 + it * 16 + il] = v;
    }
  }
}

extern "C" void kernel_launch(void* const* d_in, const int* in_sizes, int n_in,
                              void* d_out, int out_size, void* d_ws, size_t ws_size,
                              hipStream_t stream) {
  (void)in_sizes; (void)n_in; (void)out_size; (void)ws_size;
  const float* X  = (const float*)d_in[0];
  const float* Wr = (const float*)d_in[1];
  const float* br = (const float*)d_in[2];
  const float* W1 = (const float*)d_in[3];
  const float* b1 = (const float*)d_in[4];
  const float* W2 = (const float*)d_in[5];
  const float* b2 = (const float*)d_in[6];
  float* Out = (float*)d_out;

  unsigned short* Ebf = (unsigned short*)d_ws;                    // 512 KiB
  float* UVt = (float*)((char*)d_ws + (size_t)2048 * 128 * 2);    // 4 MiB
  float* cvec = (float*)((char*)d_ws + (size_t)2048 * 128 * 2 + (size_t)512 * 2048 * 4);  // 16 KiB

  gemm1_kernel<<<dim3(32, 2), 256, 0, stream>>>(X, Wr, br, Ebf);
  gemm2_kernel<<<dim3(32, 8), 256, 0, stream>>>(Ebf, W1, b1, UVt);
  cvec_kernel<<<dim3(8, 2), 256, 0, stream>>>(UVt, W2, b2, cvec);
  pairwise_kernel<<<dim3(2080, 2), 64, 0, stream>>>(UVt, W2, cvec, Out);
}

// Round 3
// 64.989 us; speedup vs baseline: 1.1013x; 1.1013x over previous
//
#include <hip/hip_runtime.h>

typedef __attribute__((ext_vector_type(4))) float f32x4;
typedef __attribute__((ext_vector_type(8))) short bf16x8;

// f32 -> bf16 round-to-nearest-even
__device__ inline unsigned short f2bf(float x) {
  unsigned u = __builtin_bit_cast(unsigned, x);
  u += 0x7fffu + ((u >> 16) & 1u);
  return (unsigned short)(u >> 16);
}

__device__ inline bf16x8 pack8(f32x4 lo, f32x4 hi) {
  bf16x8 r;
  r[0] = (short)f2bf(lo[0]); r[1] = (short)f2bf(lo[1]);
  r[2] = (short)f2bf(lo[2]); r[3] = (short)f2bf(lo[3]);
  r[4] = (short)f2bf(hi[0]); r[5] = (short)f2bf(hi[1]);
  r[6] = (short)f2bf(hi[2]); r[7] = (short)f2bf(hi[3]);
  return r;
}

// prep: convert X (768 blks), Wr (48), W1-split (32), w2h (1) -> bf16 / scaled
__global__ __launch_bounds__(256) void prep_kernel(
    const float* __restrict__ X, const float* __restrict__ Wr,
    const float* __restrict__ W1, const float* __restrict__ W2,
    unsigned short* __restrict__ Xbf, unsigned short* __restrict__ Wrbf,
    unsigned short* __restrict__ W1bf, float* __restrict__ w2h) {
  int bid = blockIdx.x, tid = threadIdx.x;
  if (bid < 768) {
    size_t o = (size_t)bid * 2048 + tid * 8;
    f32x4 a = *(const f32x4*)(X + o), b = *(const f32x4*)(X + o + 4);
    *(bf16x8*)(Xbf + o) = pack8(a, b);
  } else if (bid < 816) {
    size_t o = (size_t)(bid - 768) * 2048 + tid * 8;
    f32x4 a = *(const f32x4*)(Wr + o), b = *(const f32x4*)(Wr + o + 4);
    *(bf16x8*)(Wrbf + o) = pack8(a, b);
  } else if (bid < 848) {
    size_t o = (size_t)(bid - 816) * 2048 + tid * 8;
    int m = (int)(o >> 7), k = (int)(o & 127);
    const float* src = (m < 256) ? (W1 + (size_t)m * 256 + k)
                                 : (W1 + (size_t)(m - 256) * 256 + 128 + k);
    f32x4 a = *(const f32x4*)src, b = *(const f32x4*)(src + 4);
    *(bf16x8*)(W1bf + o) = pack8(a, b);
  } else {
    w2h[tid] = 0.5f * W2[tid];
  }
}

// GEMM1: e[2048][128] = X @ Wr^T + br (bf16 out). Wave: 16 tok x 64 n,
// direct bf16 global loads (L2-resident), no LDS, no barriers.
__global__ __launch_bounds__(256) void gemm1_kernel(
    const unsigned short* __restrict__ Xbf, const unsigned short* __restrict__ Wrbf,
    const float* __restrict__ br, unsigned short* __restrict__ Ebf) {
  int wave = threadIdx.x >> 6, lane = threadIdx.x & 63;
  int tok0 = (blockIdx.x * 4 + wave) * 16;
  int n0 = blockIdx.y * 64;
  int lr = lane & 15, kg = (lane >> 4) * 8;
  const unsigned short* ap = Xbf + (size_t)(tok0 + lr) * 768 + kg;
  const unsigned short* bp0 = Wrbf + (size_t)(n0 + lr) * 768 + kg;
  const unsigned short* bp1 = bp0 + 16 * 768;
  const unsigned short* bp2 = bp0 + 32 * 768;
  const unsigned short* bp3 = bp0 + 48 * 768;
  f32x4 acc0 = {0,0,0,0}, acc1 = {0,0,0,0}, acc2 = {0,0,0,0}, acc3 = {0,0,0,0};
#pragma unroll 4
  for (int k0 = 0; k0 < 768; k0 += 32) {
    bf16x8 a = *(const bf16x8*)(ap + k0);
    bf16x8 b0 = *(const bf16x8*)(bp0 + k0);
    bf16x8 b1 = *(const bf16x8*)(bp1 + k0);
    bf16x8 b2 = *(const bf16x8*)(bp2 + k0);
    bf16x8 b3 = *(const bf16x8*)(bp3 + k0);
    acc0 = __builtin_amdgcn_mfma_f32_16x16x32_bf16(a, b0, acc0, 0, 0, 0);
    acc1 = __builtin_amdgcn_mfma_f32_16x16x32_bf16(a, b1, acc1, 0, 0, 0);
    acc2 = __builtin_amdgcn_mfma_f32_16x16x32_bf16(a, b2, acc2, 0, 0, 0);
    acc3 = __builtin_amdgcn_mfma_f32_16x16x32_bf16(a, b3, acc3, 0, 0, 0);
  }
  int rb = (lane >> 4) * 4;
  f32x4 accs[4] = {acc0, acc1, acc2, acc3};
#pragma unroll
  for (int t = 0; t < 4; ++t) {
    int n = n0 + t * 16 + lr;
    float bias = br[n];
#pragma unroll
    for (int r = 0; r < 4; ++r)
      Ebf[(size_t)(tok0 + rb + r) * 128 + n] = f2bf(accs[t][r] + bias);
  }
}

// GEMM2 + fused cvec: UVt[512][2048] (0..255 = e@W1r^T + b1, 256..511 = e@W1c^T)
// epilogue: cvec[h][tok] += sum_m w2h[m]*val via shfl-reduce + atomicAdd
__global__ __launch_bounds__(256) void gemm2_kernel(
    const unsigned short* __restrict__ Ebf, const unsigned short* __restrict__ W1bf,
    const float* __restrict__ b1, const float* __restrict__ w2h,
    float* __restrict__ UVt, float* __restrict__ cvec) {
  int wave = threadIdx.x >> 6, lane = threadIdx.x & 63;
  int t0 = blockIdx.x * 64;
  int m0 = (blockIdx.y * 4 + wave) * 16;
  int lr = lane & 15, kg = (lane >> 4) * 8;
  const unsigned short* aB = W1bf + (size_t)(m0 + lr) * 128 + kg;
  f32x4 acc[4] = {{0,0,0,0},{0,0,0,0},{0,0,0,0},{0,0,0,0}};
#pragma unroll
  for (int k0 = 0; k0 < 128; k0 += 32) {
    bf16x8 a = *(const bf16x8*)(aB + k0);
#pragma unroll
    for (int t = 0; t < 4; ++t) {
      bf16x8 b = *(const bf16x8*)(Ebf + (size_t)(t0 + t * 16 + lr) * 128 + kg + k0);
      acc[t] = __builtin_amdgcn_mfma_f32_16x16x32_bf16(a, b, acc[t], 0, 0, 0);
    }
  }
  int rb = (lane >> 4) * 4;
  float p[4] = {0.f, 0.f, 0.f, 0.f};
#pragma unroll
  for (int t = 0; t < 4; ++t) {
#pragma unroll
    for (int r = 0; r < 4; ++r) {
      int m = m0 + rb + r;
      float val = acc[t][r] + ((m0 < 256) ? b1[m] : 0.f);
      UVt[(size_t)m * 2048 + t0 + t * 16 + lr] = val;
      p[t] = fmaf(w2h[m & 255], val, p[t]);
    }
  }
#pragma unroll
  for (int t = 0; t < 4; ++t) {
    p[t] += __shfl_xor(p[t], 16);
    p[t] += __shfl_xor(p[t], 32);
  }
  if (lane < 16) {
    int h = (m0 < 256) ? 0 : 1;
#pragma unroll
    for (int t = 0; t < 4; ++t)
      atomicAdd(&cvec[h * 2048 + t0 + t * 16 + lane], p[t]);
  }
}

// Pairwise: 32x32 tile / block, 4 waves m-split (64 m each), [m][tok] LDS,
// outer-product 4x4/lane, LDS partial combine, mirror write from symmetry.
__global__ __launch_bounds__(256) void pairwise_kernel(
    const float* __restrict__ UVt, const float* __restrict__ w2h,
    const float* __restrict__ cvec, const float* __restrict__ b2p,
    float* __restrict__ Out) {
  __shared__ float u_s[4][64][36];
  __shared__ float v_s[4][64][36];
  __shared__ float w2_s[256];
  __shared__ float cuv[64];

  int tid = threadIdx.x;
  int wave = tid >> 6, lane = tid & 63;
  int b = blockIdx.y;
  int p = blockIdx.x;
  int it = 0;
  while (p >= 32 - it) { p -= 32 - it; ++it; }
  int jt = it + p;

  int utok = b * 1024 + it * 32;
  int vtok = b * 1024 + jt * 32;

  w2_s[tid] = w2h[tid];
  if (tid < 32) cuv[tid] = cvec[utok + tid];
  else if (tid < 64) cuv[tid] = cvec[2048 + vtok + (tid - 32)];

  // stage this wave's 64-m slice: 8 rows/pass x 8 passes
  int mr = lane >> 3, tq = (lane & 7) * 4;
#pragma unroll
  for (int g = 0; g < 8; ++g) {
    int ml = g * 8 + mr;
    int m = wave * 64 + ml;
    *(f32x4*)&u_s[wave][ml][tq] = *(const f32x4*)(UVt + (size_t)m * 2048 + utok + tq);
    *(f32x4*)&v_s[wave][ml][tq] = *(const f32x4*)(UVt + (size_t)(256 + m) * 2048 + vtok + tq);
  }
  __syncthreads();

  int tx = lane & 7, ty = lane >> 3;
  float acc[4][4] = {{0,0,0,0},{0,0,0,0},{0,0,0,0},{0,0,0,0}};
  for (int ml = 0; ml < 64; ml += 4) {
    f32x4 wq = *(const f32x4*)&w2_s[wave * 64 + ml];
#pragma unroll
    for (int s = 0; s < 4; ++s) {
      f32x4 uu = *(const f32x4*)&u_s[wave][ml + s][4 * ty];
      f32x4 vv = *(const f32x4*)&v_s[wave][ml + s][4 * tx];
      float w = wq[s];
#pragma unroll
      for (int i = 0; i < 4; ++i)
#pragma unroll
        for (int j = 0; j < 4; ++j)
          acc[i][j] = fmaf(w, fabsf(uu[i] + vv[j]), acc[i][j]);
    }
  }

  // combine partials: waves 1..3 -> LDS overlay (u_s), wave 0 sums
  __syncthreads();
  float* ov = (float*)u_s;
  if (wave > 0) {
#pragma unroll
    for (int i = 0; i < 4; ++i) {
      f32x4 rowv = {acc[i][0], acc[i][1], acc[i][2], acc[i][3]};
      *(f32x4*)&ov[(((wave - 1) * 4 + i) * 64 + lane) * 4] = rowv;
    }
  }
  __syncthreads();
  if (wave == 0) {
#pragma unroll
    for (int w = 1; w < 4; ++w)
#pragma unroll
      for (int i = 0; i < 4; ++i) {
        f32x4 rowv = *(const f32x4*)&ov[(((w - 1) * 4 + i) * 64 + lane) * 4];
#pragma unroll
        for (int j = 0; j < 4; ++j) acc[i][j] += rowv[j];
      }
    float b2v = b2p[0];
    float val[4][4];
#pragma unroll
    for (int i = 0; i < 4; ++i)
#pragma unroll
      for (int j = 0; j < 4; ++j)
        val[i][j] = acc[i][j] + cuv[4 * ty + i] + cuv[32 + 4 * tx + j] + b2v;

    size_t obase = (size_t)b << 20;
    int i0 = it * 32, j0 = jt * 32;
    if (it != jt) {
      // direct tile
#pragma unroll
      for (int i = 0; i < 4; ++i) {
        f32x4 dv = {val[i][0], val[i][1], val[i][2], val[i][3]};
        *(f32x4*)(Out + obase + (size_t)(i0 + 4 * ty + i) * 1024 + j0 + 4 * tx) = dv;
      }
      // mirror tile via LDS transpose (v_s overlay, wave0-only)
      float* t32 = (float*)v_s;
#pragma unroll
      for (int i = 0; i < 4; ++i)
#pragma unroll
        for (int j = 0; j < 4; ++j)
          t32[(4 * ty + i) * 33 + 4 * tx + j] = val[i][j];
      __builtin_amdgcn_s_waitcnt(0);  // lgkm drain within wave
#pragma unroll
      for (int i = 0; i < 4; ++i) {
        f32x4 mv;
#pragma unroll
        for (int k = 0; k < 4; ++k) mv[k] = t32[(4 * tx + k) * 33 + 4 * ty + i];
        *(f32x4*)(Out + obase + (size_t)(j0 + 4 * ty + i) * 1024 + i0 + 4 * tx) = mv;
      }
    } else {
#pragma unroll
      for (int i = 0; i < 4; ++i)
#pragma unroll
        for (int j = 0; j < 4; ++j) {
          int il = 4 * ty + i, jl = 4 * tx + j;
          if (jl >= il) Out[obase + (size_t)(i0 + il) * 1024 + j0 + jl] = val[i][j];
          if (jl > il)  Out[obase + (size_t)(j0 + jl) * 1024 + i0 + il] = val[i][j];
        }
    }
  }
}

extern "C" void kernel_launch(void* const* d_in, const int* in_sizes, int n_in,
                              void* d_out, int out_size, void* d_ws, size_t ws_size,
                              hipStream_t stream) {
  (void)in_sizes; (void)n_in; (void)out_size; (void)ws_size;
  const float* X  = (const float*)d_in[0];
  const float* Wr = (const float*)d_in[1];
  const float* br = (const float*)d_in[2];
  const float* W1 = (const float*)d_in[3];
  const float* b1 = (const float*)d_in[4];
  const float* W2 = (const float*)d_in[5];
  const float* b2 = (const float*)d_in[6];
  float* Out = (float*)d_out;

  char* ws = (char*)d_ws;
  unsigned short* Xbf  = (unsigned short*)(ws);                 // 3,145,728 B
  unsigned short* Wrbf = (unsigned short*)(ws + 3145728);       //   196,608 B
  unsigned short* W1bf = (unsigned short*)(ws + 3342336);       //   131,072 B
  float*          w2h  = (float*)(ws + 3473408);                //     1,024 B
  unsigned short* Ebf  = (unsigned short*)(ws + 3474432);       //   524,288 B
  float*          UVt  = (float*)(ws + 3998720);                // 4,194,304 B
  float*          cvec = (float*)(ws + 8193024);                //    16,384 B

  prep_kernel<<<849, 256, 0, stream>>>(X, Wr, W1, W2, Xbf, Wrbf, W1bf, w2h);
  hipMemsetAsync(cvec, 0, 2 * 2048 * sizeof(float), stream);
  gemm1_kernel<<<dim3(32, 2), 256, 0, stream>>>(Xbf, Wrbf, br, Ebf);
  gemm2_kernel<<<dim3(32, 8), 256, 0, stream>>>(Ebf, W1bf, b1, w2h, UVt, cvec);
  pairwise_kernel<<<dim3(528, 2), 256, 0, stream>>>(UVt, w2h, cvec, b2, Out);
}